// Round 4
// baseline (675.479 us; speedup 1.0000x reference)
//
#include <hip/hip_runtime.h>
#include <math.h>

#define BATCH 8
#define SEQ   2048
#define CDIM  768
#define HDIM  64
#define NBLK  (SEQ / 64)   // multiplicative mask: future region dominates -> scan ALL s-blocks

typedef double d4 __attribute__((ext_vector_type(4)));

// ---------------------------------------------------------------- projection
__global__ __launch_bounds__(256) void qkv_proj_kernel(
    const float* __restrict__ x,
    const float* __restrict__ Wk,
    const float* __restrict__ Wq,
    const float* __restrict__ Wv,
    double* __restrict__ qd,
    double* __restrict__ kd,
    float*  __restrict__ vf)
{
    __shared__ float xs[32][68];
    __shared__ float wqs[64 * 64];
    __shared__ float wks[64 * 64];
    __shared__ float wvs[64 * 64];

    const int tid = threadIdx.x;
    const int tx  = tid & 15;
    const int ty  = tid >> 4;
    const size_t row0 = (size_t)blockIdx.x * 32;

    double qa[2][4] = {{0, 0, 0, 0}, {0, 0, 0, 0}};
    double ka[2][4] = {{0, 0, 0, 0}, {0, 0, 0, 0}};
    float  va[2][4] = {{0, 0, 0, 0}, {0, 0, 0, 0}};

    for (int cc = 0; cc < CDIM; cc += 64) {
        __syncthreads();
        #pragma unroll
        for (int it = 0; it < 2; ++it) {
            const int t  = tid + it * 256;
            const int r  = t >> 4;
            const int c4 = t & 15;
            const float4 v4 = *reinterpret_cast<const float4*>(
                &x[(row0 + r) * CDIM + cc + c4 * 4]);
            *reinterpret_cast<float4*>(&xs[r][c4 * 4]) = v4;
        }
        {
            const float4* wqg = reinterpret_cast<const float4*>(&Wq[(size_t)cc * HDIM]);
            const float4* wkg = reinterpret_cast<const float4*>(&Wk[(size_t)cc * HDIM]);
            const float4* wvg = reinterpret_cast<const float4*>(&Wv[(size_t)cc * HDIM]);
            float4* wql = reinterpret_cast<float4*>(wqs);
            float4* wkl = reinterpret_cast<float4*>(wks);
            float4* wvl = reinterpret_cast<float4*>(wvs);
            #pragma unroll
            for (int it = 0; it < 4; ++it) {
                const int t = tid + it * 256;
                wql[t] = wqg[t];
                wkl[t] = wkg[t];
                wvl[t] = wvg[t];
            }
        }
        __syncthreads();
        #pragma unroll 4
        for (int c = 0; c < 64; ++c) {
            const float4 wq4 = *reinterpret_cast<const float4*>(&wqs[c * 64 + tx * 4]);
            const float4 wk4 = *reinterpret_cast<const float4*>(&wks[c * 64 + tx * 4]);
            const float4 wv4 = *reinterpret_cast<const float4*>(&wvs[c * 64 + tx * 4]);
            #pragma unroll
            for (int i = 0; i < 2; ++i) {
                const float  xv = xs[ty * 2 + i][c];
                const double xd = (double)xv;
                qa[i][0] += xd * (double)wq4.x;
                qa[i][1] += xd * (double)wq4.y;
                qa[i][2] += xd * (double)wq4.z;
                qa[i][3] += xd * (double)wq4.w;
                ka[i][0] += xd * (double)wk4.x;
                ka[i][1] += xd * (double)wk4.y;
                ka[i][2] += xd * (double)wk4.z;
                ka[i][3] += xd * (double)wk4.w;
                va[i][0] += xv * wv4.x;
                va[i][1] += xv * wv4.y;
                va[i][2] += xv * wv4.z;
                va[i][3] += xv * wv4.w;
            }
        }
    }
    #pragma unroll
    for (int i = 0; i < 2; ++i) {
        const size_t row = row0 + ty * 2 + i;
        *reinterpret_cast<double2*>(&qd[row * HDIM + tx * 4])     = make_double2(qa[i][0], qa[i][1]);
        *reinterpret_cast<double2*>(&qd[row * HDIM + tx * 4 + 2]) = make_double2(qa[i][2], qa[i][3]);
        *reinterpret_cast<double2*>(&kd[row * HDIM + tx * 4])     = make_double2(ka[i][0], ka[i][1]);
        *reinterpret_cast<double2*>(&kd[row * HDIM + tx * 4 + 2]) = make_double2(ka[i][2], ka[i][3]);
        *reinterpret_cast<float4*>(&vf[row * HDIM + tx * 4]) =
            make_float4(va[i][0], va[i][1], va[i][2], va[i][3]);
    }
}

// ---------------------------------------------------------------- attention
// MFMA f64 score path with in-kernel layout verification at sb==0; block-uniform
// fallback to the proven VALU fp64 score path if the fragment convention differs.
__global__ __launch_bounds__(256, 1) void attn_kernel(
    const double* __restrict__ qd,
    const double* __restrict__ kd,
    const float*  __restrict__ vf,
    float* __restrict__ out)
{
    __shared__ double qT[64 * 64];   // [d][slot], slot = (t + d) & 63
    __shared__ double kT[64 * 64];   // [d][slot], slot = (s + d) & 63
    __shared__ float  vs[64 * 64];   // [s][d]
    __shared__ float  ps[64 * 68];   // [row][s] padded
    __shared__ float  sf_row[64];
    __shared__ float  l_row[64];
    __shared__ int    okf[4];

    const int tid  = threadIdx.x;
    const int lane = tid & 63;
    const int w    = tid >> 6;
    const int lo   = lane & 15;
    const int hi   = lane >> 4;
    const int tx   = tid & 15;
    const int ty   = tid >> 4;
    const int tb   = blockIdx.x;
    const int b    = blockIdx.y;
    const int r0   = tb * 64;

    // ---- stage qT (transpose + rotate)
    {
        const int c2 = tid & 31;
        const int rb = tid >> 5;
        const double* qsrc = qd + ((size_t)b * SEQ + r0) * HDIM;
        #pragma unroll
        for (int it = 0; it < 8; ++it) {
            const int r = rb + it * 8;
            const double2 v2 = *reinterpret_cast<const double2*>(
                &qsrc[(size_t)r * HDIM + 2 * c2]);
            const int d0 = 2 * c2, d1 = 2 * c2 + 1;
            qT[d0 * 64 + ((r + d0) & 63)] = v2.x;
            qT[d1 * 64 + ((r + d1) & 63)] = v2.y;
        }
    }

    double m[4];
    float  l[4];
    float  oacc[4][4];
    #pragma unroll
    for (int i = 0; i < 4; ++i) {
        m[i] = -1.0e300;
        l[i] = 0.f;
        #pragma unroll
        for (int j = 0; j < 4; ++j) oacc[i][j] = 0.f;
    }

    const int ubase = lo + hi;
    bool use_mfma = false;

    for (int sb = 0; sb < NBLK; ++sb) {
        __syncthreads();                 // B1
        const size_t kvbase = ((size_t)b * SEQ + sb * 64) * HDIM;
        {
            const int c2 = tid & 31;
            const int rb = tid >> 5;
            #pragma unroll
            for (int it = 0; it < 8; ++it) {
                const int r = rb + it * 8;
                const double2 v2 = *reinterpret_cast<const double2*>(
                    &kd[kvbase + (size_t)r * HDIM + 2 * c2]);
                const int d0 = 2 * c2, d1 = 2 * c2 + 1;
                kT[d0 * 64 + ((r + d0) & 63)] = v2.x;
                kT[d1 * 64 + ((r + d1) & 63)] = v2.y;
            }
            const float4* vsrc = reinterpret_cast<const float4*>(vf + kvbase);
            #pragma unroll
            for (int it = 0; it < 4; ++it) {
                const int t = tid + it * 256;
                reinterpret_cast<float4*>(vs)[t] = vsrc[t];
            }
        }
        __syncthreads();                 // B2

        if (sb == 0) {
            // probe the MFMA fragment convention once per block
            d4 dacc[4];
            #pragma unroll
            for (int j = 0; j < 4; ++j) dacc[j] = (d4){0.0, 0.0, 0.0, 0.0};
            #pragma unroll
            for (int kk = 0; kk < 16; ++kk) {
                const int d    = 4 * kk + hi;
                const int drow = d * 64;
                const int su   = ubase + 4 * kk;
                const double a = qT[drow + ((16 * w + su) & 63)];
                #pragma unroll
                for (int j = 0; j < 4; ++j) {
                    const double bv = kT[drow + ((16 * j + su) & 63)];
                    dacc[j] = __builtin_amdgcn_mfma_f64_16x16x4f64(a, bv, dacc[j], 0, 0, 0);
                }
            }
            // reference: claimed element dacc[0][0] == s[16w+4hi][lo]
            double ref = 0.0;
            const int qr = 16 * w + 4 * hi;
            for (int d = 0; d < 64; ++d) {
                const double qv = qT[d * 64 + ((qr + d) & 63)];
                const double kv = kT[d * 64 + ((lo + d) & 63)];
                ref += qv * kv;
            }
            const double got = dacc[0][0];
            const bool okl = fabs(ref - got) <= (1e-7 + 1e-9 * fabs(ref));
            const unsigned long long bal = __ballot(okl ? 1 : 0);
            if (lane == 0) okf[w] = (bal == ~0ULL) ? 1 : 0;
            __syncthreads();
            use_mfma = (okf[0] & okf[1] & okf[2] & okf[3]) != 0;

            if (use_mfma) {
                // softmax in MFMA C-layout
                #pragma unroll
                for (int i = 0; i < 4; ++i) {
                    const int rloc = 16 * w + 4 * hi + i;
                    const int rg   = r0 + rloc;
                    double lg[4];
                    double tm = -1.0e300;
                    #pragma unroll
                    for (int j = 0; j < 4; ++j) {
                        const int cg = sb * 64 + 16 * j + lo;
                        const double raw = dacc[j][i];
                        const double logit = (cg <= rg)
                            ? (raw * 1.0) * 0.125
                            : (raw * -99999999999999.0) * 0.125;
                        lg[j] = logit;
                        tm = fmax(tm, logit);
                    }
                    #pragma unroll
                    for (int off = 8; off > 0; off >>= 1)
                        tm = fmax(tm, __shfl_xor(tm, off, 16));
                    const double mnew = fmax(m[i], tm);
                    const double dm   = m[i] - mnew;
                    const float  sf   = (dm < -80.0) ? 0.f : expf((float)dm);
                    m[i] = mnew;
                    l[i] *= sf;
                    float psum = 0.f;
                    #pragma unroll
                    for (int j = 0; j < 4; ++j) {
                        const double dlt = lg[j] - mnew;
                        const float  p   = (dlt < -80.0) ? 0.f : expf((float)dlt);
                        ps[rloc * 68 + 16 * j + lo] = p;
                        psum += p;
                    }
                    #pragma unroll
                    for (int off = 8; off > 0; off >>= 1)
                        psum += __shfl_xor(psum, off, 16);
                    l[i] += psum;
                    if (lo == 0) sf_row[rloc] = sf;
                }
                goto pv_phase;
            }
            // else fall through to VALU path below
        }

        if (use_mfma) {
            d4 dacc[4];
            #pragma unroll
            for (int j = 0; j < 4; ++j) dacc[j] = (d4){0.0, 0.0, 0.0, 0.0};
            #pragma unroll
            for (int kk = 0; kk < 16; ++kk) {
                const int d    = 4 * kk + hi;
                const int drow = d * 64;
                const int su   = ubase + 4 * kk;
                const double a = qT[drow + ((16 * w + su) & 63)];
                #pragma unroll
                for (int j = 0; j < 4; ++j) {
                    const double bv = kT[drow + ((16 * j + su) & 63)];
                    dacc[j] = __builtin_amdgcn_mfma_f64_16x16x4f64(a, bv, dacc[j], 0, 0, 0);
                }
            }
            #pragma unroll
            for (int i = 0; i < 4; ++i) {
                const int rloc = 16 * w + 4 * hi + i;
                const int rg   = r0 + rloc;
                double lg[4];
                double tm = -1.0e300;
                #pragma unroll
                for (int j = 0; j < 4; ++j) {
                    const int cg = sb * 64 + 16 * j + lo;
                    const double raw = dacc[j][i];
                    const double logit = (cg <= rg)
                        ? (raw * 1.0) * 0.125
                        : (raw * -99999999999999.0) * 0.125;
                    lg[j] = logit;
                    tm = fmax(tm, logit);
                }
                #pragma unroll
                for (int off = 8; off > 0; off >>= 1)
                    tm = fmax(tm, __shfl_xor(tm, off, 16));
                const double mnew = fmax(m[i], tm);
                const double dm   = m[i] - mnew;
                const float  sf   = (dm < -80.0) ? 0.f : expf((float)dm);
                m[i] = mnew;
                l[i] *= sf;
                float psum = 0.f;
                #pragma unroll
                for (int j = 0; j < 4; ++j) {
                    const double dlt = lg[j] - mnew;
                    const float  p   = (dlt < -80.0) ? 0.f : expf((float)dlt);
                    ps[rloc * 68 + 16 * j + lo] = p;
                    psum += p;
                }
                #pragma unroll
                for (int off = 8; off > 0; off >>= 1)
                    psum += __shfl_xor(psum, off, 16);
                l[i] += psum;
                if (lo == 0) sf_row[rloc] = sf;
            }
        } else {
            // ---- proven VALU fp64 score path (reads transposed tiles)
            double s[4][4];
            #pragma unroll
            for (int i = 0; i < 4; ++i)
                #pragma unroll
                for (int j = 0; j < 4; ++j) s[i][j] = 0.0;
            #pragma unroll 2
            for (int d = 0; d < 64; ++d) {
                const int dr = d * 64;
                double qv[4], kv[4];
                #pragma unroll
                for (int i = 0; i < 4; ++i)
                    qv[i] = qT[dr + ((4 * ty + i + d) & 63)];
                #pragma unroll
                for (int j = 0; j < 4; ++j)
                    kv[j] = kT[dr + ((4 * tx + j + d) & 63)];
                #pragma unroll
                for (int i = 0; i < 4; ++i)
                    #pragma unroll
                    for (int j = 0; j < 4; ++j)
                        s[i][j] += qv[i] * kv[j];
            }
            #pragma unroll
            for (int i = 0; i < 4; ++i) {
                const int rloc = 4 * ty + i;
                const int rg   = r0 + rloc;
                double lg[4];
                double tm = -1.0e300;
                #pragma unroll
                for (int j = 0; j < 4; ++j) {
                    const int cg = sb * 64 + 4 * tx + j;
                    const double raw = s[i][j];
                    const double logit = (cg <= rg)
                        ? (raw * 1.0) * 0.125
                        : (raw * -99999999999999.0) * 0.125;
                    lg[j] = logit;
                    tm = fmax(tm, logit);
                }
                #pragma unroll
                for (int off = 8; off > 0; off >>= 1)
                    tm = fmax(tm, __shfl_xor(tm, off, 16));
                const double mnew = fmax(m[i], tm);
                const double dm   = m[i] - mnew;
                const float  sf   = (dm < -80.0) ? 0.f : expf((float)dm);
                m[i] = mnew;
                l[i] *= sf;
                float psum = 0.f;
                #pragma unroll
                for (int j = 0; j < 4; ++j) {
                    const double dlt = lg[j] - mnew;
                    const float  p   = (dlt < -80.0) ? 0.f : expf((float)dlt);
                    ps[rloc * 68 + 4 * tx + j] = p;
                    psum += p;
                }
                #pragma unroll
                for (int off = 8; off > 0; off >>= 1)
                    psum += __shfl_xor(psum, off, 16);
                l[i] += psum;
                if (tx == 0) sf_row[rloc] = sf;
            }
        }

pv_phase:
        __syncthreads();                 // B3: ps/sf visible

        float sfr[4];
        #pragma unroll
        for (int i = 0; i < 4; ++i) sfr[i] = sf_row[4 * ty + i];
        #pragma unroll
        for (int i = 0; i < 4; ++i)
            #pragma unroll
            for (int j = 0; j < 4; ++j) oacc[i][j] *= sfr[i];

        #pragma unroll 4
        for (int cs = 0; cs < 64; ++cs) {
            const float4 vv = *reinterpret_cast<const float4*>(&vs[cs * 64 + tx * 4]);
            #pragma unroll
            for (int i = 0; i < 4; ++i) {
                const float p = ps[(4 * ty + i) * 68 + cs];
                oacc[i][0] += p * vv.x;
                oacc[i][1] += p * vv.y;
                oacc[i][2] += p * vv.z;
                oacc[i][3] += p * vv.w;
            }
        }
    }

    // ---- epilogue: publish l in row order, then write output
    if (use_mfma) {
        #pragma unroll
        for (int i = 0; i < 4; ++i)
            if (lo == 0) l_row[16 * w + 4 * hi + i] = l[i];
    } else {
        #pragma unroll
        for (int i = 0; i < 4; ++i)
            if (tx == 0) l_row[4 * ty + i] = l[i];
    }
    __syncthreads();

    #pragma unroll
    for (int i = 0; i < 4; ++i) {
        const float inv = 1.0f / l_row[4 * ty + i];
        const size_t row = (size_t)b * SEQ + r0 + 4 * ty + i;
        *reinterpret_cast<float4*>(&out[row * HDIM + tx * 4]) =
            make_float4(oacc[i][0] * inv, oacc[i][1] * inv,
                        oacc[i][2] * inv, oacc[i][3] * inv);
    }
}

extern "C" void kernel_launch(void* const* d_in, const int* in_sizes, int n_in,
                              void* d_out, int out_size, void* d_ws, size_t ws_size,
                              hipStream_t stream)
{
    const float* x  = (const float*)d_in[0];
    const float* Wk = (const float*)d_in[1];
    const float* Wq = (const float*)d_in[2];
    const float* Wv = (const float*)d_in[3];
    float* out = (float*)d_out;

    double* qd = (double*)d_ws;
    double* kd = qd + (size_t)BATCH * SEQ * HDIM;
    float*  vf = (float*)(kd + (size_t)BATCH * SEQ * HDIM);

    qkv_proj_kernel<<<dim3(512), dim3(256), 0, stream>>>(x, Wk, Wq, Wv, qd, kd, vf);
    attn_kernel<<<dim3(32, 8), dim3(256), 0, stream>>>(qd, kd, vf, out);
}

// Round 6
// 396.779 us; speedup vs baseline: 1.7024x; 1.7024x over previous
//
#include <hip/hip_runtime.h>
#include <math.h>

#define BATCH 8
#define SEQ   2048
#define CDIM  768
#define HDIM  64
#define QROWS 32
#define NBLK  (SEQ / 64)   // multiplicative mask: future region dominates -> scan ALL s-blocks

typedef float f4 __attribute__((ext_vector_type(4)));
typedef short s8 __attribute__((ext_vector_type(8)));

// swizzled slot for d-pair dp within a 64-double LDS row; grp = row>>2.
// Same scheme as the round-2 kernel (measured: 0 bank conflicts).
static __device__ __forceinline__ int swz_off(int dp, int grp) {
    return ((dp + grp) & 31) * 2;
}
// round-to-nearest-even f32 -> bf16 bits
static __device__ __forceinline__ unsigned bf16_rne(float f) {
    unsigned u = __float_as_uint(f);
    return (u + 0x7FFFu + ((u >> 16) & 1u)) >> 16;
}

// ---------------------------------------------------------------- projection
// 512 blocks x 256 threads; each block computes q,k (fp64) and v (fp32) for 32 rows.
__global__ __launch_bounds__(256) void qkv_proj_kernel(
    const float* __restrict__ x,
    const float* __restrict__ Wk,
    const float* __restrict__ Wq,
    const float* __restrict__ Wv,
    double* __restrict__ qd,
    double* __restrict__ kd,
    float*  __restrict__ vf)
{
    __shared__ float xs[32][68];
    __shared__ float wqs[64 * 64];
    __shared__ float wks[64 * 64];
    __shared__ float wvs[64 * 64];

    const int tid = threadIdx.x;
    const int tx  = tid & 15;
    const int ty  = tid >> 4;
    const size_t row0 = (size_t)blockIdx.x * 32;

    double qa[2][4] = {{0, 0, 0, 0}, {0, 0, 0, 0}};
    double ka[2][4] = {{0, 0, 0, 0}, {0, 0, 0, 0}};
    float  va[2][4] = {{0, 0, 0, 0}, {0, 0, 0, 0}};

    for (int cc = 0; cc < CDIM; cc += 64) {
        __syncthreads();
        #pragma unroll
        for (int it = 0; it < 2; ++it) {
            const int t  = tid + it * 256;
            const int r  = t >> 4;
            const int c4 = t & 15;
            const float4 v4 = *reinterpret_cast<const float4*>(
                &x[(row0 + r) * CDIM + cc + c4 * 4]);
            *reinterpret_cast<float4*>(&xs[r][c4 * 4]) = v4;
        }
        {
            const float4* wqg = reinterpret_cast<const float4*>(&Wq[(size_t)cc * HDIM]);
            const float4* wkg = reinterpret_cast<const float4*>(&Wk[(size_t)cc * HDIM]);
            const float4* wvg = reinterpret_cast<const float4*>(&Wv[(size_t)cc * HDIM]);
            float4* wql = reinterpret_cast<float4*>(wqs);
            float4* wkl = reinterpret_cast<float4*>(wks);
            float4* wvl = reinterpret_cast<float4*>(wvs);
            #pragma unroll
            for (int it = 0; it < 4; ++it) {
                const int t = tid + it * 256;
                wql[t] = wqg[t];
                wkl[t] = wkg[t];
                wvl[t] = wvg[t];
            }
        }
        __syncthreads();
        #pragma unroll 4
        for (int c = 0; c < 64; ++c) {
            const float4 wq4 = *reinterpret_cast<const float4*>(&wqs[c * 64 + tx * 4]);
            const float4 wk4 = *reinterpret_cast<const float4*>(&wks[c * 64 + tx * 4]);
            const float4 wv4 = *reinterpret_cast<const float4*>(&wvs[c * 64 + tx * 4]);
            #pragma unroll
            for (int i = 0; i < 2; ++i) {
                const float  xv = xs[ty * 2 + i][c];
                const double xd = (double)xv;
                qa[i][0] += xd * (double)wq4.x;
                qa[i][1] += xd * (double)wq4.y;
                qa[i][2] += xd * (double)wq4.z;
                qa[i][3] += xd * (double)wq4.w;
                ka[i][0] += xd * (double)wk4.x;
                ka[i][1] += xd * (double)wk4.y;
                ka[i][2] += xd * (double)wk4.z;
                ka[i][3] += xd * (double)wk4.w;
                va[i][0] += xv * wv4.x;
                va[i][1] += xv * wv4.y;
                va[i][2] += xv * wv4.z;
                va[i][3] += xv * wv4.w;
            }
        }
    }
    #pragma unroll
    for (int i = 0; i < 2; ++i) {
        const size_t row = row0 + ty * 2 + i;
        *reinterpret_cast<double2*>(&qd[row * HDIM + tx * 4])     = make_double2(qa[i][0], qa[i][1]);
        *reinterpret_cast<double2*>(&qd[row * HDIM + tx * 4 + 2]) = make_double2(qa[i][2], qa[i][3]);
        *reinterpret_cast<double2*>(&kd[row * HDIM + tx * 4])     = make_double2(ka[i][0], ka[i][1]);
        *reinterpret_cast<double2*>(&kd[row * HDIM + tx * 4 + 2]) = make_double2(ka[i][2], ka[i][3]);
        *reinterpret_cast<float4*>(&vf[row * HDIM + tx * 4]) =
            make_float4(va[i][0], va[i][1], va[i][2], va[i][3]);
    }
}

// ---------------------------------------------------------------- attention
// grid (64, 8): 32 q-rows per block, 256 threads, 2 blocks/CU (69 KB LDS).
// Scores: round-2-proven fp64 VALU path. PV: bf16 mfma_f32_16x16x32 (verified
// C/D layout), p stored bf16 in XOR-swizzled LDS, v converted on the fly.
__global__ __launch_bounds__(256, 2) void attn_kernel(
    const double* __restrict__ qd,
    const double* __restrict__ kd,
    const float*  __restrict__ vf,
    float* __restrict__ out)
{
    __shared__ __align__(16) double qs[QROWS * 64];   // swizzled [r][d]
    __shared__ __align__(16) double ks[64 * 64];      // swizzled [s][d]
    __shared__ __align__(16) float  vs[64 * 66];      // [s][d], stride 66 (bank spread)
    __shared__ __align__(16) unsigned short ps[QROWS * 64]; // bf16 P, XOR-swizzled rows
    __shared__ float sf_row[QROWS];
    __shared__ float l_row[QROWS];

    const int tid  = threadIdx.x;
    const int lane = tid & 63;
    const int w    = tid >> 6;      // wave 0..3
    const int lo   = lane & 15;     // MFMA m/n lane index
    const int hi   = lane >> 4;     // MFMA k-chunk / C row group
    const int tx   = tid & 15;      // score col group (4tx..)
    const int ty   = tid >> 4;      // score row group (2ty..), 0..15
    const int tb   = blockIdx.x;    // 0..63
    const int b    = blockIdx.y;    // 0..7
    const int r0   = tb * QROWS;

    const int c2 = tid & 31;        // staging d-pair
    const int rb = tid >> 5;        // staging row base

    // ---- stage q tile (swizzled, 32 rows)
    {
        const double* qsrc = qd + ((size_t)b * SEQ + r0) * HDIM;
        #pragma unroll
        for (int it = 0; it < 4; ++it) {
            const int r = rb + it * 8;
            const double2 v2 = *reinterpret_cast<const double2*>(
                &qsrc[(size_t)r * HDIM + 2 * c2]);
            *reinterpret_cast<double2*>(&qs[r * 64 + swz_off(c2, r >> 2)]) = v2;
        }
    }

    double m[2];
    float  l[2];
    f4     acc[2];                   // 2 d-tiles x 4 rows, MFMA C layout
    m[0] = m[1] = -1.0e300;
    l[0] = l[1] = 0.f;
    acc[0] = (f4){0.f, 0.f, 0.f, 0.f};
    acc[1] = (f4){0.f, 0.f, 0.f, 0.f};

    // ---- prefetch registers for K/V staging (T14: issue early, write late)
    double2 kreg[8];
    float4  vreg[4];
    {
        const size_t kvbase = (size_t)b * SEQ * HDIM;
        #pragma unroll
        for (int it = 0; it < 8; ++it)
            kreg[it] = *reinterpret_cast<const double2*>(
                &kd[kvbase + (size_t)(rb + it * 8) * HDIM + 2 * c2]);
        #pragma unroll
        for (int it = 0; it < 4; ++it) {
            const int t = tid + it * 256;
            vreg[it] = *reinterpret_cast<const float4*>(
                &vf[kvbase + (size_t)(t >> 4) * HDIM + (t & 15) * 4]);
        }
    }
    // write sb=0 staging
    #pragma unroll
    for (int it = 0; it < 8; ++it) {
        const int r = rb + it * 8;
        *reinterpret_cast<double2*>(&ks[r * 64 + swz_off(c2, r >> 2)]) = kreg[it];
    }
    #pragma unroll
    for (int it = 0; it < 4; ++it) {
        const int t = tid + it * 256;
        const int s = t >> 4, c4 = t & 15;
        const int base = s * 66 + 4 * c4;
        *reinterpret_cast<float2*>(&vs[base])     = make_float2(vreg[it].x, vreg[it].y);
        *reinterpret_cast<float2*>(&vs[base + 2]) = make_float2(vreg[it].z, vreg[it].w);
    }
    __syncthreads();                 // B2: staging visible

    const int qg = ty >> 1;          // both rows 2ty,2ty+1 share r>>2
    const int mt = w & 1;            // PV m-tile (rows 16mt..16mt+15)
    const int nh = w >> 1;           // PV d-half

    for (int sb = 0; sb < NBLK; ++sb) {
        // ---- issue next tile's global loads (hide under scores/softmax/PV)
        if (sb + 1 < NBLK) {
            const size_t kvbase = ((size_t)b * SEQ + (size_t)(sb + 1) * 64) * HDIM;
            #pragma unroll
            for (int it = 0; it < 8; ++it)
                kreg[it] = *reinterpret_cast<const double2*>(
                    &kd[kvbase + (size_t)(rb + it * 8) * HDIM + 2 * c2]);
            #pragma unroll
            for (int it = 0; it < 4; ++it) {
                const int t = tid + it * 256;
                vreg[it] = *reinterpret_cast<const float4*>(
                    &vf[kvbase + (size_t)(t >> 4) * HDIM + (t & 15) * 4]);
            }
        }

        // ---- scores (fp64 VALU, round-2 path): s[i][j] = q[2ty+i] . k[4tx+j]
        double s[2][4];
        #pragma unroll
        for (int i = 0; i < 2; ++i)
            #pragma unroll
            for (int j = 0; j < 4; ++j) s[i][j] = 0.0;

        #pragma unroll 4
        for (int dp = 0; dp < 32; ++dp) {
            const int qo = swz_off(dp, qg);
            const int ko = swz_off(dp, tx);
            const double2 q0 = *reinterpret_cast<const double2*>(&qs[(2 * ty)     * 64 + qo]);
            const double2 q1 = *reinterpret_cast<const double2*>(&qs[(2 * ty + 1) * 64 + qo]);
            #pragma unroll
            for (int j = 0; j < 4; ++j) {
                const double2 kv = *reinterpret_cast<const double2*>(&ks[(4 * tx + j) * 64 + ko]);
                s[0][j] += q0.x * kv.x + q0.y * kv.y;
                s[1][j] += q1.x * kv.x + q1.y * kv.y;
            }
        }

        // ---- faithful multiplicative mask + online softmax (fp64 logit domain)
        #pragma unroll
        for (int i = 0; i < 2; ++i) {
            const int rloc = 2 * ty + i;
            const int rg   = r0 + rloc;
            double lg[4];
            double tm = -1.0e300;
            #pragma unroll
            for (int j = 0; j < 4; ++j) {
                const int cg = sb * 64 + 4 * tx + j;
                const double raw = s[i][j];
                const double logit = (cg <= rg)
                    ? (raw * 1.0) * 0.125
                    : (raw * -99999999999999.0) * 0.125;
                lg[j] = logit;
                tm = fmax(tm, logit);
            }
            #pragma unroll
            for (int off = 8; off > 0; off >>= 1)
                tm = fmax(tm, __shfl_xor(tm, off, 16));
            const double mnew = fmax(m[i], tm);
            const double dm   = m[i] - mnew;
            const float  sf   = (dm < -80.0) ? 0.f : expf((float)dm);
            m[i] = mnew;
            l[i] *= sf;
            float p[4];
            float psum = 0.f;
            #pragma unroll
            for (int j = 0; j < 4; ++j) {
                const double dlt = lg[j] - mnew;
                p[j] = (dlt < -80.0) ? 0.f : expf((float)dlt);
                psum += p[j];
            }
            // packed bf16 writes into XOR-swizzled ps (conflict-free across tx)
            {
                const unsigned xr = (unsigned)((rloc & 7) << 4);
                char* base = reinterpret_cast<char*>(ps) + rloc * 128;
                const unsigned w0 = bf16_rne(p[0]) | (bf16_rne(p[1]) << 16);
                const unsigned w1 = bf16_rne(p[2]) | (bf16_rne(p[3]) << 16);
                *reinterpret_cast<unsigned*>(base + (((unsigned)(8 * tx))     ^ xr)) = w0;
                *reinterpret_cast<unsigned*>(base + (((unsigned)(8 * tx + 4)) ^ xr)) = w1;
            }
            #pragma unroll
            for (int off = 8; off > 0; off >>= 1)
                psum += __shfl_xor(psum, off, 16);
            l[i] += psum;
            if (tx == 0) sf_row[rloc] = sf;
        }
        __syncthreads();             // B3: ps/sf visible

        // ---- PV on bf16 MFMA: wave = (m-tile mt, d-half nh), 4 MFMA per sb
        #pragma unroll
        for (int i = 0; i < 4; ++i) {
            const float sfr = sf_row[16 * mt + 4 * hi + i];
            acc[0][i] *= sfr;
            acc[1][i] *= sfr;
        }
        #pragma unroll
        for (int ks_ = 0; ks_ < 2; ++ks_) {
            const int arow  = 16 * mt + lo;                      // A: m = lane&15
            // logical byte of k-chunk: 64*ks_ (32 elems * 2B) + 16*hi (8 elems * 2B).
            // ROUND-5 BUG WAS HERE: 32*ks_ made A's upper-K half read s=16..47
            // while B read s=32..63 — mismatched P/V.
            const unsigned abyte = (unsigned)(arow * 128)
                + (((unsigned)(64 * ks_ + 16 * hi)) ^ ((unsigned)((arow & 7) << 4)));
            const s8 af = *reinterpret_cast<const s8*>(
                reinterpret_cast<const char*>(ps) + abyte);
            const int kb = 32 * ks_ + 8 * hi;                    // B: k-chunk (elements)
            #pragma unroll
            for (int ntl = 0; ntl < 2; ++ntl) {
                const int dcol = 16 * (2 * nh + ntl) + lo;       // B: n = lane&15
                union { unsigned u[4]; s8 v; } bu;
                #pragma unroll
                for (int e2 = 0; e2 < 4; ++e2) {
                    const float f0 = vs[(kb + 2 * e2)     * 66 + dcol];
                    const float f1 = vs[(kb + 2 * e2 + 1) * 66 + dcol];
                    bu.u[e2] = bf16_rne(f0) | (bf16_rne(f1) << 16);
                }
                acc[ntl] = __builtin_amdgcn_mfma_f32_16x16x32_bf16(af, bu.v, acc[ntl], 0, 0, 0);
            }
        }
        __syncthreads();             // B1: PV reads done, safe to overwrite ks/vs/ps

        // ---- write next tile's staging from prefetch regs
        if (sb + 1 < NBLK) {
            #pragma unroll
            for (int it = 0; it < 8; ++it) {
                const int r = rb + it * 8;
                *reinterpret_cast<double2*>(&ks[r * 64 + swz_off(c2, r >> 2)]) = kreg[it];
            }
            #pragma unroll
            for (int it = 0; it < 4; ++it) {
                const int t = tid + it * 256;
                const int s_ = t >> 4, c4 = t & 15;
                const int base = s_ * 66 + 4 * c4;
                *reinterpret_cast<float2*>(&vs[base])     = make_float2(vreg[it].x, vreg[it].y);
                *reinterpret_cast<float2*>(&vs[base + 2]) = make_float2(vreg[it].z, vreg[it].w);
            }
            __syncthreads();         // B2: staging visible
        }
    }

    // ---- epilogue: publish l per row, then write output from MFMA C layout
    if (tx == 0) {
        l_row[2 * ty]     = l[0];
        l_row[2 * ty + 1] = l[1];
    }
    __syncthreads();

    #pragma unroll
    for (int ntl = 0; ntl < 2; ++ntl) {
        const int d = 16 * (2 * nh + ntl) + lo;
        #pragma unroll
        for (int i = 0; i < 4; ++i) {
            const int row = 16 * mt + 4 * hi + i;
            out[((size_t)b * SEQ + r0 + row) * HDIM + d] = acc[ntl][i] / l_row[row];
        }
    }
}

extern "C" void kernel_launch(void* const* d_in, const int* in_sizes, int n_in,
                              void* d_out, int out_size, void* d_ws, size_t ws_size,
                              hipStream_t stream)
{
    const float* x  = (const float*)d_in[0];
    const float* Wk = (const float*)d_in[1];
    const float* Wq = (const float*)d_in[2];
    const float* Wv = (const float*)d_in[3];
    float* out = (float*)d_out;

    // workspace layout: q (fp64) | k (fp64) | v (fp32)  — 20 MB total
    double* qd = (double*)d_ws;
    double* kd = qd + (size_t)BATCH * SEQ * HDIM;
    float*  vf = (float*)(kd + (size_t)BATCH * SEQ * HDIM);

    qkv_proj_kernel<<<dim3(512), dim3(256), 0, stream>>>(x, Wk, Wq, Wv, qd, kd, vf);
    attn_kernel<<<dim3(SEQ / QROWS, BATCH), dim3(256), 0, stream>>>(qd, kd, vf, out);
}